// Round 11
// baseline (296.068 us; speedup 1.0000x reference)
//
#include <hip/hip_runtime.h>
#include <hip/hip_bf16.h>

// B=512, I=1152, K=8, L=16, O=7; IK=9216, LO=112.
// Round-10: 6 dispatches -> 4 by FUSING g INTO sq via linearity (no sync):
//   u_vj(i,l) = sum_{k,o} w * G[ik][o,l] is linear in G, and G decomposes
//   over b-slices. Each sq block owns a 16-b x 16-n tile of v -> it computes
//   its partial G (576 zero-padded 16x16x32 MFMAs vs its in-LDS v-tile),
//   contracts with w locally, atomicAdds partial u_vj*(1/512) into a bij
//   INCREMENT buffer. Sum over 256 blocks == exact g result.
//   Next dispatch's prologue: read bij (18KB), exp -> csl (LDS), Z = col-sum
//   -> in-register B-scaling (R0-proven numerics). No g kernel, no vT, no
//   wps, no Z buffer.
//   bij double-buffered: it0 atomics->buf0; it1 reads buf0, atomics->buf1;
//   it2 reads buf0+buf1 (iter-3 update dead). Every dispatch only reads
//   buffers completed by earlier dispatches -> race-free.
// Chain: prep | sqg(0) | sqg(1) | sqg(2,out). Boundary count 6 -> 4.
//   prep0: x->xbf,xT (bf16) + wpT build + bij0/bij1 zero.
//   sqg(it): prologue(csl,zi) | GEMM1 s = xbf.(wpT*csl) 8-wave K-split |
//            LDS reduce, Z-div, squash | it<2: partial-G MFMA + w-contract
//            + bij atomics ; it==2: write out.
// wpT pad rows (o==7) are exact zeros (w-contract also guards o==7).

#define NB 512
#define NI 1152
#define NLO 112
#define NIK 9216
#define NPAD 128             // padded N: n = l*8+o, o==7 is zero pad

typedef __attribute__((ext_vector_type(8))) short bf16x8;
typedef __attribute__((ext_vector_type(4))) float f32x4;

__device__ __forceinline__ ushort f2bf(float f) {
    __hip_bfloat16 h = __float2bfloat16(f);
    return *(ushort*)&h;
}
__device__ __forceinline__ float bf2f(short s) {
    union { unsigned int u; float f; } v;
    v.u = ((unsigned int)(unsigned short)s) << 16;
    return v.f;
}

// ---- conv_x body: x fp32 -> xbf [b][ik] and xT [ik][b], both bf16 ----
__device__ __forceinline__ void conv_x_body(const float* __restrict__ x,
                                            ushort* __restrict__ xbf,
                                            ushort* __restrict__ xT, int bid) {
    __shared__ ushort tile[64][68];
    int kg = bid % 144, bg = bid / 144;
    int k0 = kg * 64, b0 = bg * 64;
    int t = threadIdx.x;
    for (int e = t; e < 1024; e += 256) {
        int r = e >> 4, c4 = (e & 15) * 4;
        float4 f = *(const float4*)&x[(size_t)(b0 + r) * NIK + k0 + c4];
        ushort4 u = { f2bf(f.x), f2bf(f.y), f2bf(f.z), f2bf(f.w) };
        *(ushort4*)&xbf[(size_t)(b0 + r) * NIK + k0 + c4] = u;
        tile[r][c4] = u.x; tile[r][c4 + 1] = u.y; tile[r][c4 + 2] = u.z; tile[r][c4 + 3] = u.w;
    }
    __syncthreads();
    for (int e = t; e < 1024; e += 256) {
        int kr = e >> 4, c4 = (e & 15) * 4;
        ushort4 u = { tile[c4][kr], tile[c4 + 1][kr], tile[c4 + 2][kr], tile[c4 + 3][kr] };
        *(ushort4*)&xT[(size_t)(k0 + kr) * NB + b0 + c4] = u;
    }
}

// ---- prep0: conv_x (0..1151) + wpT build + bij0/1 zero (1152..1295) ----
__global__ __launch_bounds__(256) void prep0(const float* __restrict__ x,
                                             ushort* __restrict__ xbf,
                                             ushort* __restrict__ xT,
                                             const float* __restrict__ w,
                                             ushort* __restrict__ wpT,
                                             float* __restrict__ bij0,
                                             float* __restrict__ bij1) {
    if (blockIdx.x < 1152) { conv_x_body(x, xbf, xT, blockIdx.x); return; }
    __shared__ ushort tile[NPAD][66];
    int t = threadIdx.x;
    int wb = blockIdx.x - 1152;      // 0..143
    int ik0 = wb * 64;
    if (t < 128) {                   // zero this block's bij rows (8 i's)
        bij0[wb * 128 + t] = 0.f;
        bij1[wb * 128 + t] = 0.f;
    }
    for (int e = t; e < 8192; e += 256) {
        int ikl = e >> 7, np = e & 127;
        int l = np >> 3, o = np & 7;
        float wv = (o < 7) ? w[(size_t)(ik0 + ikl) * NLO + l * 7 + o] : 0.f;
        tile[np][ikl] = f2bf(wv);
    }
    __syncthreads();
    for (int e = t; e < 8192; e += 256) {
        int np = e >> 6, ikl = e & 63;
        wpT[(size_t)np * NIK + ik0 + ikl] = tile[np][ikl];
    }
}

// ---- sqg: softmax-prologue + s-GEMM + squash + (it<2: partial-G + bij) ----
// 256 blocks x 512 thr (8 waves). Block (mt=bid&31, ng=bid>>5) owns b-rows
// [16mt,+16) x n-cols [16ng,+16) (l in {2ng,2ng+1}, all o).
__global__ __launch_bounds__(512, 2) void sqg(const ushort* __restrict__ xbf,
                                              const ushort* __restrict__ xT,
                                              const ushort* __restrict__ wpT,
                                              const float* __restrict__ w,
                                              const float* __restrict__ bijA,
                                              float* __restrict__ bijW,
                                              float* __restrict__ out, int it) {
    __shared__ float csl[NI * 2];      // 9.2 KB  [i][lsel]
    __shared__ float sp[8][16][16];    // 8 KB
    __shared__ float ss[16][16];
    __shared__ float facs[16][2];
    __shared__ float zp[512];
    __shared__ float zfin[2];
    int bid = blockIdx.x;
    int t = threadIdx.x;
    int wv = t >> 6, lane = t & 63;
    int row = lane & 15, quad = lane >> 4;
    int mt = bid & 31, ng = bid >> 5;
    int b0 = mt * 16, n0 = ng * 16;
    int k0 = wv * 1152;                // 8-way K-split of 9216
    int lsel = row >> 3;

    // ---- prologue: csl = exp(bij state) for this block's 2 l-cols, Z ----
    float zacc = 0.f;
    if (it == 0) {
        for (int e = t; e < NI * 2; e += 512) csl[e] = 1.0f;
    } else {
        for (int e = t; e < NI * 2; e += 512) {   // e&1 == t&1 (stride even)
            int i = e >> 1, lg = ng * 2 + (e & 1);
            float v = bijA[i * 16 + lg];
            if (it == 2) v += bijW[i * 16 + lg];  // bijW holds it-1 increment
            float c = expf(v);
            csl[e] = c; zacc += c;
        }
    }
    zp[t] = zacc;
    __syncthreads();
    #pragma unroll
    for (int s = 256; s >= 2; s >>= 1) {   // parity-preserving tree
        if (t < s) zp[t] += zp[t + s];
        __syncthreads();
    }
    if (t < 2) zfin[t] = (it == 0) ? (1.0f / 1152.0f) : 1.0f / zp[t];
    __syncthreads();

    // ---- GEMM1: s = xbf . (wpT scaled in-register by csl) ----
    const ushort* ap = xbf + (size_t)(b0 + row) * NIK + k0 + quad * 8;
    const ushort* bp = wpT + (size_t)(n0 + row) * NIK + k0 + quad * 8;
    int ibase = 144 * wv + quad;           // i of fragment at ks=0
    f32x4 acc = {0.f, 0.f, 0.f, 0.f};
    #pragma unroll 6
    for (int ks = 0; ks < 36; ++ks) {      // 1152/32
        bf16x8 a = *(const bf16x8*)(ap + ks * 32);
        bf16x8 wf = *(const bf16x8*)(bp + ks * 32);
        float cv = csl[(ibase + ks * 4) * 2 + lsel];
        bf16x8 b;
        #pragma unroll
        for (int j = 0; j < 8; ++j) b[j] = (short)f2bf(bf2f(wf[j]) * cv);
        acc = __builtin_amdgcn_mfma_f32_16x16x32_bf16(a, b, acc, 0, 0, 0);
    }
    #pragma unroll
    for (int r = 0; r < 4; ++r) sp[wv][quad * 4 + r][row] = acc[r];
    __syncthreads();
    if (t < 256) {
        int m = t >> 4, n = t & 15;
        float sv = 0.f;
        #pragma unroll
        for (int w8 = 0; w8 < 8; ++w8) sv += sp[w8][m][n];
        ss[m][n] = sv * zfin[n >> 3];
    }
    __syncthreads();
    if (t < 32) {
        int m = t >> 1, ll = t & 1;
        float sq = 0.f;
        #pragma unroll
        for (int o = 0; o < 8; ++o) { float e = ss[m][ll * 8 + o]; sq += e * e; }
        facs[m][ll] = sqrtf(sq) / (1.0f + sq);   // == (sq/(1+sq))/norm
    }
    __syncthreads();

    if (it == 2) {                     // final iteration: just write out
        if (t < 256) {
            int m = t >> 4, n = t & 15;
            int o = n & 7, lg = ng * 2 + (n >> 3);
            if (o < 7)
                out[(size_t)(b0 + m) * NLO + o * 16 + lg] = ss[m][n] * facs[m][n >> 3];
        }
        return;
    }

    // ---- partial-G + w-contract + bij atomics (fused g) ----
    // B-frag (constant across tiles): B[n=lane&15][k=quad*8+j]; real b_local
    // = k for k<16 (quads 0,1), zero-pad k>=16 (quads 2,3). v = squash(ss).
    int o2 = row & 7, ls2 = lsel;
    bf16x8 bfv;
    if (quad < 2) {
        #pragma unroll
        for (int j = 0; j < 8; ++j) {
            int bl = quad * 8 + j;
            float vv = (o2 == 7) ? 0.f : ss[bl][row] * facs[bl][ls2];
            bfv[j] = (short)f2bf(vv);
        }
    } else {
        #pragma unroll
        for (int j = 0; j < 8; ++j) bfv[j] = 0;
    }
    // per-lane w coefficients base (fixed l,o); o==7 lanes contribute 0
    const float* wbase = w + (size_t)0 * NLO + (ng * 2 + ls2) * 7 + o2;
    f32x4 zero4 = {0.f, 0.f, 0.f, 0.f};
    int rep = ((quad & 1) == 0) && (o2 == 0);
    int lg2 = ng * 2 + ls2;
    for (int j = 0; j < 72; ++j) {         // 576 tiles / 8 waves
        int tl = wv * 72 + j;
        int ik0t = tl * 16;
        bf16x8 af;
        if (quad < 2)
            af = *(const bf16x8*)(xT + (size_t)(ik0t + row) * NB + b0 + quad * 8);
        else {
            #pragma unroll
            for (int q = 0; q < 8; ++q) af[q] = 0;
        }
        f32x4 g = __builtin_amdgcn_mfma_f32_16x16x32_bf16(af, bfv, zero4, 0, 0, 0);
        // lane holds G[ik_local=quad*4+r][n=row]
        float p = 0.f;
        if (o2 < 7) {
            const float* wr = wbase + (size_t)(ik0t + quad * 4) * NLO;
            #pragma unroll
            for (int r = 0; r < 4; ++r) p += g[r] * wr[(size_t)r * NLO];
        }
        p += __shfl_xor(p, 16);            // quad-pair: sum 8 ik -> i_local
        p += __shfl_xor(p, 1);             // o-rows (o==7 lane holds 0)
        p += __shfl_xor(p, 2);
        p += __shfl_xor(p, 4);
        if (rep)                           // lanes 0,8,32,40
            atomicAdd(&bijW[(tl * 2 + (quad >> 1)) * 16 + lg2], p * (1.0f / 512.0f));
    }
}

extern "C" void kernel_launch(void* const* d_in, const int* in_sizes, int n_in,
                              void* d_out, int out_size, void* d_ws, size_t ws_size,
                              hipStream_t stream) {
    const float* x = (const float*)d_in[0];   // [512][9216]
    const float* w = (const float*)d_in[1];   // [9216][112]
    float* out = (float*)d_out;               // [512][112]
    float* ws = (float*)d_ws;
    float*  bij0 = ws;                                    // 18432
    float*  bij1 = bij0 + NI * 16;                        // 18432
    ushort* xbf  = (ushort*)(bij1 + NI * 16);             // 512*9216
    ushort* xT   = xbf + (size_t)NB * NIK;                // 9216*512
    ushort* wpT  = xT + (size_t)NIK * NB;                 // 128*9216 static
    prep0<<<1296, 256, 0, stream>>>(x, xbf, xT, w, wpT, bij0, bij1);
    // it0: csl=1, atomics -> bij0
    sqg<<<256, 512, 0, stream>>>(xbf, xT, wpT, w, bij1, bij0, out, 0);
    // it1: read bij0, atomics -> bij1
    sqg<<<256, 512, 0, stream>>>(xbf, xT, wpT, w, bij0, bij1, out, 1);
    // it2: read bij0+bij1, write out
    sqg<<<256, 512, 0, stream>>>(xbf, xT, wpT, w, bij0, bij1, out, 2);
}

// Round 12
// 174.762 us; speedup vs baseline: 1.6941x; 1.6941x over previous
//
#include <hip/hip_runtime.h>
#include <hip/hip_bf16.h>

// B=512, I=1152, K=8, L=16, O=7; IK=9216, LO=112.
// FINAL (Round-11): revert to the Round-3 configuration -- the session's
// best measured result (172.65 us). Eleven rounds established:
//  - 6-dispatch total is INSENSITIVE to kernel internals (4 different sq/g
//    implementations all land 172.6-176 us).
//  - All fusion variants regress: cg grid.sync = system-scope L2/L3 flush
//    (~45us/sync); hand-rolled barriers leave phases L2-cold (L2 does not
//    survive kernel boundaries either -- implicit acquire at launch);
//    per-block partial-G fusion serializes into a latency chain (105us).
//  - Floor composition: ~44us harness poison fill (in timed window) +
//    6 launch boundaries (implicit cross-XCD L2 invalidate, ~8-12us each)
//    + small latency-bound kernel bodies. Not a memory/compute roofline;
//    structural overhead unreachable from kernel source.
// Structure:
//   prep0: x->xbf,xT (bf16) + wpT/wps = bf16(w) padded (STATIC) + Z init
//   sq_gemm: s = xbf . wps (pre-scaled B), 8-wave K-split, 6-deep ring
//            prefetch, LDS reduce, Z-divide + squash -> vT (+out last)
//   g_wc: G = xT.vT MFMA -> w-contract -> bij -> cs=exp -> Z + wps rescale
// Softmax deferred: wps carries unnormalized exp, sq divides by Z_l.
// wps pad rows (o==7) are exact zeros. Iter-3 bij update dead -> skipped.

#define NB 512
#define NI 1152
#define NLO 112
#define NIK 9216
#define NPAD 128             // padded N: n = l*8+o, o==7 is zero pad

typedef __attribute__((ext_vector_type(8))) short bf16x8;
typedef __attribute__((ext_vector_type(4))) float f32x4;

__device__ __forceinline__ ushort f2bf(float f) {
    __hip_bfloat16 h = __float2bfloat16(f);
    return *(ushort*)&h;
}
__device__ __forceinline__ float bf2f(short s) {
    union { unsigned int u; float f; } v;
    v.u = ((unsigned int)(unsigned short)s) << 16;
    return v.f;
}

// ---- conv_x body: x fp32 -> xbf [b][ik] and xT [ik][b], both bf16 ----
__device__ __forceinline__ void conv_x_body(const float* __restrict__ x,
                                            ushort* __restrict__ xbf,
                                            ushort* __restrict__ xT, int bid) {
    __shared__ ushort tile[64][68];
    int kg = bid % 144, bg = bid / 144;
    int k0 = kg * 64, b0 = bg * 64;
    int t = threadIdx.x;
    for (int e = t; e < 1024; e += 256) {
        int r = e >> 4, c4 = (e & 15) * 4;
        float4 f = *(const float4*)&x[(size_t)(b0 + r) * NIK + k0 + c4];
        ushort4 u = { f2bf(f.x), f2bf(f.y), f2bf(f.z), f2bf(f.w) };
        *(ushort4*)&xbf[(size_t)(b0 + r) * NIK + k0 + c4] = u;
        tile[r][c4] = u.x; tile[r][c4 + 1] = u.y; tile[r][c4 + 2] = u.z; tile[r][c4 + 3] = u.w;
    }
    __syncthreads();
    for (int e = t; e < 1024; e += 256) {
        int kr = e >> 4, c4 = (e & 15) * 4;
        ushort4 u = { tile[c4][kr], tile[c4 + 1][kr], tile[c4 + 2][kr], tile[c4 + 3][kr] };
        *(ushort4*)&xT[(size_t)(k0 + kr) * NB + b0 + c4] = u;
    }
}

// ---- prep0: conv_x (0..1151) + static wpT/wps build + Z init (1152..1295) ----
__global__ __launch_bounds__(256) void prep0(const float* __restrict__ x,
                                             ushort* __restrict__ xbf,
                                             ushort* __restrict__ xT,
                                             const float* __restrict__ w,
                                             ushort* __restrict__ wpT,
                                             ushort* __restrict__ wps,
                                             float* __restrict__ Z) {
    if (blockIdx.x < 1152) { conv_x_body(x, xbf, xT, blockIdx.x); return; }
    __shared__ ushort tile[NPAD][66];
    int t = threadIdx.x;
    int wb = blockIdx.x - 1152;      // 0..143
    int ik0 = wb * 64;
    if (blockIdx.x == 1152 && t < 48) Z[t] = (t < 16) ? 1152.0f : 0.0f;
    for (int e = t; e < 8192; e += 256) {
        int ikl = e >> 7, np = e & 127;
        int l = np >> 3, o = np & 7;
        float wv = (o < 7) ? w[(size_t)(ik0 + ikl) * NLO + l * 7 + o] : 0.f;
        tile[np][ikl] = f2bf(wv);
    }
    __syncthreads();
    for (int e = t; e < 8192; e += 256) {
        int np = e >> 6, ikl = e & 63;
        ushort v = tile[np][ikl];
        wpT[(size_t)np * NIK + ik0 + ikl] = v;   // static master copy
        wps[(size_t)np * NIK + ik0 + ikl] = v;   // iter-0 scaled copy (eb=1)
    }
}

// ---- sq_gemm: fused s-GEMM + Z-divide + squash -> vT/out ----
// 256 blocks x 512 thr (8 waves, K-split 9216/8=1152 -> 36 K-steps/wave).
// __launch_bounds__(512,2): VGPR ceiling 256 so the 6-deep ring prefetch
// stays in registers (12 outstanding 16B loads/wave).
__global__ __launch_bounds__(512, 2) void sq_gemm(const ushort* __restrict__ xbf,
                                                  const ushort* __restrict__ wps,
                                                  const float* __restrict__ Zit,
                                                  ushort* __restrict__ vT,
                                                  float* __restrict__ out, int wout) {
    __shared__ float sp[8][16][16];    // [wave][m][n] 8 KB
    __shared__ float ss[16][16];
    __shared__ float facs[16][2];
    __shared__ float zi[2];
    int bid = blockIdx.x;
    int mt = bid & 31, ng = bid >> 5;
    int b0 = mt * 16, n0 = ng * 16;
    int t = threadIdx.x;
    int wv = t >> 6, lane = t & 63;
    int row = lane & 15, quad = lane >> 4;
    int k0 = wv * 1152;                // 8-way K-split of 9216
    if (t < 2) zi[t] = 1.0f / Zit[ng * 2 + t];
    const ushort* ap = xbf + (size_t)(b0 + row) * NIK + k0 + quad * 8;
    const ushort* bp = wps + (size_t)(n0 + row) * NIK + k0 + quad * 8;
    // 6-deep ring prefetch; fully unrolled -> all ring indices static
    bf16x8 ab[6], bb[6];
    #pragma unroll
    for (int p = 0; p < 6; ++p) {
        ab[p] = *(const bf16x8*)(ap + p * 32);
        bb[p] = *(const bf16x8*)(bp + p * 32);
    }
    f32x4 acc = {0.f, 0.f, 0.f, 0.f};
    #pragma unroll
    for (int ks = 0; ks < 36; ++ks) {  // 1152/32
        int s = ks % 6;
        acc = __builtin_amdgcn_mfma_f32_16x16x32_bf16(ab[s], bb[s], acc, 0, 0, 0);
        if (ks < 30) {
            ab[s] = *(const bf16x8*)(ap + (ks + 6) * 32);
            bb[s] = *(const bf16x8*)(bp + (ks + 6) * 32);
        }
    }
    #pragma unroll
    for (int r = 0; r < 4; ++r) sp[wv][quad * 4 + r][row] = acc[r];
    __syncthreads();
    if (t < 256) {
        int m = t >> 4, n = t & 15;
        float sv = 0.f;
        #pragma unroll
        for (int w8 = 0; w8 < 8; ++w8) sv += sp[w8][m][n];
        ss[m][n] = sv * zi[n >> 3];
    }
    __syncthreads();
    if (t < 32) {
        int m = t >> 1, ll = t & 1;
        float sq = 0.f;
        #pragma unroll
        for (int o = 0; o < 8; ++o) { float e = ss[m][ll * 8 + o]; sq += e * e; }
        facs[m][ll] = sqrtf(sq) / (1.0f + sq);   // == (sq/(1+sq))/norm; pad adds 0
    }
    __syncthreads();
    if (t < 256) {
        int m = t >> 4, n = t & 15;
        int o = n & 7, lg = ng * 2 + (n >> 3);
        if (o < 7) {
            float vv = ss[m][n] * facs[m][n >> 3];
            vT[(size_t)(o * 16 + lg) * NB + b0 + m] = f2bf(vv);
            if (wout) out[(size_t)(b0 + m) * NLO + o * 16 + lg] = vv;
        }
    }
}

// ---- g_wc: G-MFMA + w-contraction + block-local bij update + eb=exp + Z
//      + wps rescale for the next iteration. 144 blocks x 512 threads. ----
// block owns i = blockIdx.x*8 .. +7 (ik = 64*bid .. +63) exclusively ->
// plain bij/wps writes, atomics only on Z.
__global__ __launch_bounds__(512) void g_wc(const ushort* __restrict__ xT,
                                            const ushort* __restrict__ vT,
                                            const float* __restrict__ w,
                                            float* __restrict__ bij,
                                            const ushort* __restrict__ wpT,
                                            ushort* __restrict__ wps,
                                            float* __restrict__ Zit, int accum) {
    __shared__ float bs[2][8][16];
    __shared__ float cs[128];
    int t = threadIdx.x;
    int wv = t >> 6;                 // 0..7
    int lane = t & 63;
    int half = wv & 1;
    int mt = wv >> 1;                // 0..3
    int m0 = blockIdx.x * 64 + mt * 16;
    int kb0 = half * 256;
    int row = lane & 15, quad = lane >> 4;
    const ushort* ap = xT + (size_t)(m0 + row) * NB + kb0 + quad * 8;
    const ushort* bp = vT + (size_t)row * NB + kb0 + quad * 8;    // + nt*16*NB
    f32x4 acc[7];
    #pragma unroll
    for (int nt = 0; nt < 7; ++nt) acc[nt] = (f32x4){0.f, 0.f, 0.f, 0.f};
    // load-use interleave: one A-frag + one B-frag live at a time
    for (int ks = 0; ks < 8; ++ks) {                 // 256/32
        bf16x8 a = *(const bf16x8*)(ap + ks * 32);
        #pragma unroll
        for (int nt = 0; nt < 7; ++nt) {
            bf16x8 bfr = *(const bf16x8*)(bp + (size_t)nt * 16 * NB + ks * 32);
            acc[nt] = __builtin_amdgcn_mfma_f32_16x16x32_bf16(a, bfr, acc[nt], 0, 0, 0);
        }
    }
    // lane holds G[ik = m0+quad*4+r][o*16+l], o = nt, l = row
    float S = 0.f;
    #pragma unroll
    for (int r = 0; r < 4; ++r) {
        int ik = m0 + quad * 4 + r;
        const float* wr = w + (size_t)ik * NLO + row * 7;
        float p = 0.f;
        #pragma unroll
        for (int o = 0; o < 7; ++o) p += wr[o] * acc[o][r];
        S += p;
    }
    float Sp = __shfl_down(S, 16);                   // partner quad's 4-ik sum
    if ((quad & 1) == 0)
        bs[half][mt * 2 + (quad >> 1)][row] = (S + Sp) * (1.0f / 512.0f);
    __syncthreads();
    if (t < 128) {
        int il = t >> 4, l = t & 15;
        int i = blockIdx.x * 8 + il;
        float val = bs[0][il][l] + bs[1][il][l];
        if (accum) val += bij[i * 16 + l];
        bij[i * 16 + l] = val;
        cs[t] = expf(val);           // cs[il*16 + l]
    }
    __syncthreads();
    if (t < 16) {
        float z = 0.f;
        #pragma unroll
        for (int j = 0; j < 8; ++j) z += cs[j * 16 + t];
        atomicAdd(&Zit[t], z);
    }
    // rescale this block's 64 ik-columns: wps = bf16(cs * wpT) for next iter.
    int ik0 = blockIdx.x * 64;
    for (int e = t; e < 2048; e += 512) {
        int np = e >> 4, i4 = (e & 15) * 4;
        float sc = cs[(i4 >> 3) * 16 + (np >> 3)];
        ushort4 wv4 = *(const ushort4*)&wpT[(size_t)np * NIK + ik0 + i4];
        ushort4 o4 = { f2bf(bf2f((short)wv4.x) * sc), f2bf(bf2f((short)wv4.y) * sc),
                       f2bf(bf2f((short)wv4.z) * sc), f2bf(bf2f((short)wv4.w) * sc) };
        *(ushort4*)&wps[(size_t)np * NIK + ik0 + i4] = o4;
    }
}

extern "C" void kernel_launch(void* const* d_in, const int* in_sizes, int n_in,
                              void* d_out, int out_size, void* d_ws, size_t ws_size,
                              hipStream_t stream) {
    const float* x = (const float*)d_in[0];   // [512][9216]
    const float* w = (const float*)d_in[1];   // [9216][112]
    float* out = (float*)d_out;               // [512][112]
    float* ws = (float*)d_ws;
    float*  f_bij  = ws;                                  // 18432
    float*  f_Z    = f_bij + NI * 16;                     // 3*16
    ushort* xbf    = (ushort*)(f_Z + 48);                 // 512*9216
    ushort* xT     = xbf + (size_t)NB * NIK;              // 9216*512
    ushort* wpT    = xT + (size_t)NIK * NB;               // 128*9216 static
    ushort* wps    = wpT + (size_t)NPAD * NIK;            // 128*9216 scaled
    ushort* vT     = wps + (size_t)NPAD * NIK;            // 112*512
    prep0<<<1296, 256, 0, stream>>>(x, xbf, xT, w, wpT, wps, f_Z);
    for (int it = 0; it < 3; ++it) {
        sq_gemm<<<256, 512, 0, stream>>>(xbf, wps, f_Z + it * 16, vT, out,
                                         it == 2 ? 1 : 0);
        if (it < 2)
            g_wc<<<144, 512, 0, stream>>>(xT, vT, w, f_bij, wpT, wps,
                                          f_Z + (it + 1) * 16, it);
    }
}